// Round 9
// baseline (437.658 us; speedup 1.0000x reference)
//
#include <hip/hip_runtime.h>
#include <cstdint>

#define IN_F  1024
#define OUT_F 1024
#define NORD  13
#define BROWS 8192   // 4*2048

typedef __bf16 bf16x8 __attribute__((ext_vector_type(8)));
typedef float  f32x4  __attribute__((ext_vector_type(4)));
typedef unsigned short u16x8 __attribute__((ext_vector_type(8)));
typedef unsigned short u16x4 __attribute__((ext_vector_type(4)));

__device__ __forceinline__ unsigned short f2bf(float f) {
  unsigned int u = __float_as_uint(f);
  unsigned int r = u + 0x7FFFu + ((u >> 16) & 1u);
  return (unsigned short)(r >> 16);
}
__device__ __forceinline__ float bf2f(unsigned short h) {
  return __uint_as_float(((unsigned int)h) << 16);
}
__device__ __forceinline__ float bfround(float f) { return bf2f(f2bf(f)); }

// fast tanh: tanh(x) = 1 - 2/(e^{2x}+1); exact saturation at +-inf.
// Validated rounds 2/5/6/8 (all passed, absmax unchanged at 0.078125).
__device__ __forceinline__ float fast_tanh(float x) {
  float e = __expf(2.0f * x);
  return 1.0f - 2.0f / (e + 1.0f);
}

// global -> LDS async copy, 16B per lane.
__device__ __forceinline__ void gload_lds16(const void* g, void* l) {
  __builtin_amdgcn_global_load_lds(
      (__attribute__((address_space(1))) unsigned int*)(uintptr_t)g,
      (__attribute__((address_space(3))) unsigned int*)(unsigned int)(uintptr_t)l,
      16, 0, 0);
}

// ---------------- FUSED prep: bias + weight-transpose + activation in ONE launch ------------
// Block roles by blockIdx.x range (small latency-bound roles first so they dispatch early and
// hide under act's memory wave): [0,nBias) bias, [nBias,nBias+nWp) wprep, rest act.
// All role bodies are byte-identical math to the previously-verified separate kernels:
//  * bias: exact bias1+bias2 summation order (8 chunk sums, f ascending; chunks summed asc).
//  * wprep: same 64x65 LDS transpose; flat remap tx=t&63, ty=t>>6 preserves lane mapping.
//  * act:   same silu/Chebyshev recursion and store pattern.
// Writes are disjoint; gemm consumes only after this node completes. Occupancy: 256-thread
// blocks are thread-limited to 8 blocks/CU, so the 16.6KB LDS tile costs act nothing.
__global__ __launch_bounds__(256)
void prep_kernel(const float* __restrict__ x, const float* __restrict__ baseW,
                 const float* __restrict__ poly, unsigned short* __restrict__ A,
                 unsigned short* __restrict__ Wt, float* __restrict__ bias,
                 int b0, int nb, int Kp, int nBias, int nWp) {
  __shared__ float tile[64][65];
  int bid = blockIdx.x;
  int t   = threadIdx.x;

  if (bid < nBias) {
    // ---- bias role: bias[n] = colsum of bf16(pw0), exact bias1/bias2 order ----
    int n = bid * 256 + t;
    float ch[8];
#pragma unroll
    for (int fc = 0; fc < 8; fc++) ch[fc] = 0.f;
    for (int fo = 0; fo < 128; fo++) {
#pragma unroll
      for (int fc = 0; fc < 8; fc++)
        ch[fc] += bf2f(f2bf(poly[(size_t)(fc * 128 + fo) * OUT_F + n]));
    }
    float s = 0.f;
#pragma unroll
    for (int fc = 0; fc < 8; fc++) s += ch[fc];
    bias[n] = s;
    return;
  }

  if (bid < nBias + nWp) {
    // ---- wprep role: Wt[n][bb*1024+f] = bf16(src_b[f][n]) ----
    int rid = bid - nBias;
    int bb  = rid >> 8;            // 256 blocks per order
    int rem = rid & 255;
    int n0  = (rem & 15) * 64, f0 = (rem >> 4) * 64;
    int g   = b0 + bb;
    const float* src = (g == 0) ? baseW : (poly + (size_t)g * (IN_F * OUT_F));
    int tx = t & 63, ty = t >> 6;  // 64 x 4
#pragma unroll
    for (int i = 0; i < 16; i++)
      tile[ty + i * 4][tx] = src[(size_t)(f0 + ty + i * 4) * OUT_F + n0 + tx];
    __syncthreads();               // uniform within block (role is per-block)
#pragma unroll
    for (int i = 0; i < 16; i++)
      Wt[(size_t)(n0 + ty + i * 4) * Kp + (size_t)bb * 1024 + f0 + tx] = f2bf(tile[tx][ty + i * 4]);
    return;
  }

  // ---- act role: A[row][bb*1024+f] (bf16) ----
  int aid = bid - nBias - nWp;
  int row = aid * 2 + (t >> 7);
  int f0  = (t & 127) * 8;
  const float* xr = x + (size_t)row * IN_F + f0;
  float xv[8];
  *(float4*)&xv[0] = *(const float4*)&xr[0];
  *(float4*)&xv[4] = *(const float4*)&xr[4];
  unsigned short* Ar = A + (size_t)row * Kp;
  int omax = b0 + nb - 1;
  if (b0 == 0) {
    // JAX bf16 silu: sigmoid rounded to bf16, then x*sigmoid rounded to bf16
    u16x8 sv;
#pragma unroll
    for (int i = 0; i < 8; i++) {
      float xc = bfround(xv[i]);
      float sg = bfround(1.0f / (1.0f + __expf(-xc)));
      sv[i] = f2bf(xc * sg);
    }
    *(u16x8*)&Ar[f0] = sv;
  }
  float xs2[8], tp[8], tc[8];
#pragma unroll
  for (int i = 0; i < 8; i++) {
    float xs = fast_tanh(xv[i]);
    tp[i] = 1.0f; tc[i] = xs; xs2[i] = xs + xs;
  }
  for (int o = 1; o <= omax; o++) {
    if (o >= b0) {
      int bb = o - b0;
      u16x8 sv;
#pragma unroll
      for (int i = 0; i < 8; i++) sv[i] = f2bf(tc[i]);
      *(u16x8*)&Ar[(size_t)bb * 1024 + f0] = sv;
    }
    {
#pragma clang fp contract(off)
#pragma unroll
      for (int i = 0; i < 8; i++) {
        float tm = xs2[i] * tc[i];
        float tn = tm - tp[i];
        tp[i] = tc[i]; tc[i] = tn;
      }
    }
  }
}

// ---------------- GEMM: CHAMPION (round-0) -- double-buffered LDS, 1 barrier/kt ------------
// 128x128 tile, BK=64, 4 waves of 64x64, 2 blocks/CU. Grid (64 m-tiles, 8 n-tiles):
// id%8 == m%8 -> A-strip sharers co-locate on one XCD. bf16 accumulation-chain emulated at
// 1024-K boundaries. Measured: ~245 us, 901 TF, MfmaUtil 40%, 0 bank conflicts.
// Structure-space verdict (rounds 1-7): every alternative (counted-vmcnt, tri-buffer,
// A-to-reg, 256-tile, 4-phase+setprio, 128x64-wave) regressed or tied -- this is the
// shape-constrained plain-HIP optimum (m201's regime needs 16384 outputs/SIMD; we have 8192).
__global__ __launch_bounds__(256, 2)
void gemm_kernel(const unsigned short* __restrict__ A, const unsigned short* __restrict__ Wt,
                 unsigned short* __restrict__ outAcc, const float* __restrict__ bias,
                 int Kp, int isFirst) {
  __shared__ unsigned short sA[2][128 * 64];  // 2 x 16 KB
  __shared__ unsigned short sB[2][128 * 64];  // 2 x 16 KB
  int t    = threadIdx.x;
  int m0   = blockIdx.x * 128;
  int n0   = blockIdx.y * 128;
  int wave = t >> 6, lane = t & 63;
  int lr   = lane & 15, quad = lane >> 4;
  int wm   = (wave & 1) * 64, wn = (wave >> 1) * 64;

  int rs = t >> 3;
  int jg = (t & 7) ^ (rs & 7);
  const unsigned short* aSrc = A  + (size_t)(m0 + rs) * Kp + jg * 8;
  const unsigned short* bSrc = Wt + (size_t)(n0 + rs) * Kp + jg * 8;
  char* sAc = (char*)sA;
  char* sBc = (char*)sB;
  int ldsOff = t * 16;

  int aOff[4][2], bOff[4][2];
#pragma unroll
  for (int mi = 0; mi < 4; mi++) {
    int row = wm + mi * 16 + lr;
#pragma unroll
    for (int ks = 0; ks < 2; ks++) {
      int j = ks * 4 + quad;
      aOff[mi][ks] = row * 128 + ((j ^ (row & 7)) * 16);
    }
  }
#pragma unroll
  for (int ni = 0; ni < 4; ni++) {
    int row = wn + ni * 16 + lr;
#pragma unroll
    for (int ks = 0; ks < 2; ks++) {
      int j = ks * 4 + quad;
      bOff[ni][ks] = row * 128 + ((j ^ (row & 7)) * 16);
    }
  }

  // running bf16-valued sum s
  f32x4 s[4][4];
  float bsr[4];
  if (isFirst) {
#pragma unroll
    for (int ni = 0; ni < 4; ni++) bsr[ni] = bfround(bias[n0 + wn + ni * 16 + lr]);
  } else {
#pragma unroll
    for (int ni = 0; ni < 4; ni++) {
      int gn = n0 + wn + ni * 16 + lr;
#pragma unroll
      for (int mi = 0; mi < 4; mi++) {
        int gmBase = m0 + wm + mi * 16 + quad * 4;
#pragma unroll
        for (int r = 0; r < 4; r++)
          s[mi][ni][r] = bf2f(outAcc[(size_t)(gmBase + r) * OUT_F + gn]);
      }
    }
  }

  int nKt  = Kp >> 6;    // 64-K steps
  int nBlk = Kp >> 10;   // 1024-K order blocks

  // stage tile gkt into buffer buf
  auto stage = [&](int gkt, int buf) {
    const unsigned short* aP = aSrc + gkt * 64;
    const unsigned short* bP = bSrc + gkt * 64;
    char* dA = sAc + buf * 16384 + ldsOff;
    char* dB = sBc + buf * 16384 + ldsOff;
#pragma unroll
    for (int rd = 0; rd < 4; rd++)
      gload_lds16(aP + (size_t)rd * 32 * Kp, dA + rd * 4096);
#pragma unroll
    for (int rd = 0; rd < 4; rd++)
      gload_lds16(bP + (size_t)rd * 32 * Kp, dB + rd * 4096);
  };

  stage(0, 0);  // prologue

  int gkt = 0;
  for (int blk = 0; blk < nBlk; blk++) {
    f32x4 acc[4][4];
#pragma unroll
    for (int mi = 0; mi < 4; mi++)
#pragma unroll
      for (int ni = 0; ni < 4; ni++)
        acc[mi][ni] = (f32x4){0.f, 0.f, 0.f, 0.f};

    for (int kt = 0; kt < 16; kt++, gkt++) {
      __syncthreads();               // drains vmcnt for tile gkt (issued 1 iter ago)
      int nxt = gkt + 1;
      if (nxt < nKt) stage(nxt, nxt & 1);   // prefetch: full compute phase to land
      int buf = gkt & 1;
      char* bA = sAc + buf * 16384;
      char* bB = sBc + buf * 16384;
#pragma unroll
      for (int ks = 0; ks < 2; ks++) {
        bf16x8 af[4], bfr[4];
#pragma unroll
        for (int mi = 0; mi < 4; mi++) af[mi] = *(const bf16x8*)(bA + aOff[mi][ks]);
#pragma unroll
        for (int ni = 0; ni < 4; ni++) bfr[ni] = *(const bf16x8*)(bB + bOff[ni][ks]);
#pragma unroll
        for (int mi = 0; mi < 4; mi++)
#pragma unroll
          for (int ni = 0; ni < 4; ni++)
            acc[mi][ni] = __builtin_amdgcn_mfma_f32_16x16x32_bf16(af[mi], bfr[ni], acc[mi][ni], 0, 0, 0);
      }
    }

    // bf16 chain update at the order-block boundary (matches ref rounding)
    bool firstBlk = (isFirst && blk == 0);
    if (firstBlk) {
#pragma unroll
      for (int mi = 0; mi < 4; mi++)
#pragma unroll
        for (int ni = 0; ni < 4; ni++)
#pragma unroll
          for (int r = 0; r < 4; r++) {
            float p = bfround(acc[mi][ni][r]);          // out = bf16 matmul result
            s[mi][ni][r] = bfround(p + bsr[ni]);        // out = bf16(out + bf16(bias))
          }
    } else {
#pragma unroll
      for (int mi = 0; mi < 4; mi++)
#pragma unroll
        for (int ni = 0; ni < 4; ni++)
#pragma unroll
          for (int r = 0; r < 4; r++)
            s[mi][ni][r] = bfround(s[mi][ni][r] + bfround(acc[mi][ni][r]));
    }
  }

  // store running sum as bf16 (values are exactly bf16-representable)
#pragma unroll
  for (int ni = 0; ni < 4; ni++) {
    int gn = n0 + wn + ni * 16 + lr;
#pragma unroll
    for (int mi = 0; mi < 4; mi++) {
      int gmBase = m0 + wm + mi * 16 + quad * 4;
#pragma unroll
      for (int r = 0; r < 4; r++)
        outAcc[(size_t)(gmBase + r) * OUT_F + gn] = f2bf(s[mi][ni][r]);
    }
  }
}

// ---------------- RMSNorm on bf16 outAcc ----------------
__global__ __launch_bounds__(256)
void rms_kernel(const unsigned short* __restrict__ outAcc, const float* __restrict__ scale,
                float* __restrict__ out) {
  int row = blockIdx.x;
  int t   = threadIdx.x;
  const unsigned short* src = outAcc + (size_t)row * OUT_F;
  u16x4 hv = *(const u16x4*)&src[t * 4];
  float v[4];
#pragma unroll
  for (int i = 0; i < 4; i++) v[i] = bf2f(hv[i]);
  float s = v[0]*v[0] + v[1]*v[1] + v[2]*v[2] + v[3]*v[3];
#pragma unroll
  for (int off = 32; off > 0; off >>= 1) s += __shfl_down(s, off, 64);
  __shared__ float red[4];
  if ((t & 63) == 0) red[t >> 6] = s;
  __syncthreads();
  float tot = red[0] + red[1] + red[2] + red[3];
  float sc = 1.0f / sqrtf(tot * (1.0f / OUT_F) + 1e-6f);
  float4 so = *(const float4*)&scale[t * 4];
  float4 o;
  o.x = v[0] * sc * so.x; o.y = v[1] * sc * so.y;
  o.z = v[2] * sc * so.z; o.w = v[3] * sc * so.w;
  *(float4*)&out[(size_t)row * OUT_F + t * 4] = o;
}

extern "C" void kernel_launch(void* const* d_in, const int* in_sizes, int n_in,
                              void* d_out, int out_size, void* d_ws, size_t ws_size,
                              hipStream_t stream) {
  const float* x     = (const float*)d_in[0];
  const float* baseW = (const float*)d_in[1];
  const float* poly  = (const float*)d_in[2];
  const float* scale = (const float*)d_in[3];
  float* out = (float*)d_out;

  char* ws = (char*)d_ws;
  unsigned short* outAcc = (unsigned short*)ws;        // 8192*1024*2 = 16777216 B
  float* bias    = (float*)(ws + 16777216);            // 4096 B
  size_t fixed   = 16777216 + 4096;

  int CHB = 1;
  for (int c = NORD; c >= 1; c--) {
    size_t need = fixed + (size_t)c * 1024 * OUT_F * 2
                + (size_t)BROWS * c * 1024 * 2;
    if (need <= ws_size) { CHB = c; break; }
  }
  unsigned short* Wt = (unsigned short*)(ws + fixed);
  unsigned short* Ap = (unsigned short*)(ws + fixed + (size_t)CHB * 1024 * OUT_F * 2);

  for (int b0 = 0; b0 < NORD; b0 += CHB) {
    int nb = (CHB < NORD - b0) ? CHB : (NORD - b0);
    int Kp = nb * 1024;
    int nBias = (b0 == 0) ? 4 : 0;     // bias only needed once (isFirst chunk)
    int nWp   = 256 * nb;              // 16x16 tiles per order
    prep_kernel<<<nBias + nWp + BROWS / 2, 256, 0, stream>>>(
        x, baseW, poly, Ap, Wt, bias, b0, nb, Kp, nBias, nWp);
    gemm_kernel<<<dim3(BROWS / 128, 8), 256, 0, stream>>>(Ap, Wt, outAcc, bias, Kp, (b0 == 0) ? 1 : 0);
  }
  rms_kernel<<<BROWS, 256, 0, stream>>>(outAcc, scale, out);
}